// Round 1
// baseline (934.386 us; speedup 1.0000x reference)
//
#include <hip/hip_runtime.h>

// Problem constants
#define BB 16
#define CIN 32
#define NN 4096
#define TT 12
#define HH 64
#define MM 128
#define DD 64
#define TC (TT*HH)            // 768
#define OUT0 50331648         // B*H*N*T
#define V1OFF 50331648
#define V2OFF 50855936
#define KVELEM (MM*TC)        // 98304 per batch
#define NORMR 0.35355339059327373f   // 64^-0.25
#define RATIO 0.08838834764831845f   // 128^-0.5
#define FEPS 1e-4f

__device__ inline float wave_max(float v) {
#pragma unroll
  for (int off = 32; off > 0; off >>= 1) v = fmaxf(v, __shfl_xor(v, off));
  return v;
}

__device__ inline unsigned short f2bf(float f) {
  unsigned int u = __float_as_uint(f);
  unsigned int r = (u + 0x7FFFu + ((u >> 16) & 1u)) >> 16;
  return (unsigned short)r;
}

// K1: per-row features. v1p written final; t2 = dash2-diag2 stored in v2p slot
// (finished in-place by K3); per-row max of dash2 -> rowmax2.
__global__ __launch_bounds__(128) void k_feat(const float* __restrict__ nv1,
    const float* __restrict__ nv2, const float* __restrict__ proj,
    float* __restrict__ v1p, float* __restrict__ t2, float* __restrict__ rowmax2) {
  int n = blockIdx.x, m = threadIdx.x;
  __shared__ float a1[DD], a2[DD], r1[2], r2[2];
  if (m < DD) a1[m] = nv1[n * DD + m];
  else        a2[m - DD] = nv2[n * DD + (m - DD)];
  __syncthreads();
  float s1 = 0.f, s2 = 0.f, d1 = 0.f, d2 = 0.f;
  const float* pr = proj + m * DD;
#pragma unroll 8
  for (int d = 0; d < DD; d++) {
    float x1 = a1[d], x2 = a2[d], p = pr[d];
    s1 += x1 * x1; s2 += x2 * x2;
    d1 += x1 * p;  d2 += x2 * p;
  }
  d1 *= NORMR; d2 *= NORMR;
  float diag1 = 0.0625f * s1, diag2 = 0.0625f * s2;  // 0.5*sum*norm^2
  float mx1 = wave_max(d1), mx2 = wave_max(d2);
  int wv = m >> 6;
  if ((m & 63) == 0) { r1[wv] = mx1; r2[wv] = mx2; }
  __syncthreads();
  mx1 = fmaxf(r1[0], r1[1]); mx2 = fmaxf(r2[0], r2[1]);
  v1p[n * MM + m] = RATIO * (__expf(d1 - diag1 - mx1) + FEPS);
  t2[n * MM + m] = d2 - diag2;
  if (m == 0) rowmax2[n] = mx2;
}

// K2: global max of dash2
__global__ __launch_bounds__(256) void k_stab(const float* __restrict__ rowmax2,
                                              float* __restrict__ stab2) {
  int tid = threadIdx.x;
  float mx = -3.4e38f;
  for (int i = tid; i < NN; i += 256) mx = fmaxf(mx, rowmax2[i]);
  mx = wave_max(mx);
  __shared__ float r[4];
  if ((tid & 63) == 0) r[tid >> 6] = mx;
  __syncthreads();
  if (tid == 0) stab2[0] = fmaxf(fmaxf(r[0], r[1]), fmaxf(r[2], r[3]));
}

// K3: finish v2p in place, accumulate column sums
__global__ __launch_bounds__(128) void k_v2p(float* __restrict__ t2v2p,
    const float* __restrict__ stab2, float* __restrict__ colsum) {
  int m = threadIdx.x;
  float stab = stab2[0];
  float cs = 0.f;
  for (int n = blockIdx.x; n < NN; n += gridDim.x) {
    float v = RATIO * (__expf(t2v2p[n * MM + m] - stab) + FEPS);
    t2v2p[n * MM + m] = v;
    cs += v;
  }
  atomicAdd(&colsum[m], cs);
}

// K4: inv_den[n] = 1 / (v1p[n,:] . colsum)
__global__ __launch_bounds__(256) void k_den(const float* __restrict__ v1p,
    const float* __restrict__ colsum, float* __restrict__ invden) {
  __shared__ float cs[MM];
  int tid = threadIdx.x;
  if (tid < MM) cs[tid] = colsum[tid];
  __syncthreads();
  int n = blockIdx.x * 256 + tid;
  const float* vp = v1p + (size_t)n * MM;
  float s = 0.f;
#pragma unroll 8
  for (int m = 0; m < MM; m++) s += vp[m] * cs[m];
  invden[n] = 1.0f / s;
}

// K5: fused 1x1-conv + sigmoid gate -> x stashed as bf16 at front of d_out.
// block = 384 threads = 32 n x 12 t; each thread does all 64 hid channels.
__global__ __launch_bounds__(384) void k_point(const float* __restrict__ inp,
    const float* __restrict__ Wi, const float* __restrict__ bi,
    const float* __restrict__ Wo, const float* __restrict__ bo,
    unsigned short* __restrict__ xst) {
  __shared__ float sWi[CIN][HH];  // [c][o] transposed
  __shared__ float sWo[CIN][HH];
  __shared__ float sbi[HH], sbo[HH];
  int tid = threadIdx.x;
  for (int i = tid; i < HH * CIN; i += 384) {
    int o = i >> 5, c = i & 31;
    sWi[c][o] = Wi[i];
    sWo[c][o] = Wo[i];
  }
  if (tid < HH) { sbi[tid] = bi[tid]; sbo[tid] = bo[tid]; }
  __syncthreads();
  int nl = tid / TT, t = tid - nl * TT;
  int n = blockIdx.x * 32 + nl;
  int b = blockIdx.y;
  const float* ip = inp + ((size_t)(b * CIN) * NN + n) * TT + t;
  float xin[CIN];
#pragma unroll
  for (int c = 0; c < CIN; c++) xin[c] = ip[(size_t)c * (NN * TT)];
  unsigned short* xp = xst + ((size_t)(b * NN + n)) * TC + t * HH;
#pragma unroll
  for (int half = 0; half < 2; half++) {
    int ob = half * 32;
    float h1[32], h2[32];
#pragma unroll
    for (int o = 0; o < 32; o++) { h1[o] = sbi[ob + o]; h2[o] = sbo[ob + o]; }
    for (int c = 0; c < CIN; c++) {
      float v = xin[c];
      const float4* w1 = (const float4*)&sWi[c][ob];
      const float4* w2 = (const float4*)&sWo[c][ob];
#pragma unroll
      for (int q = 0; q < 8; q++) {
        float4 a = w1[q], bb = w2[q];
        h1[q * 4 + 0] += a.x * v;  h1[q * 4 + 1] += a.y * v;
        h1[q * 4 + 2] += a.z * v;  h1[q * 4 + 3] += a.w * v;
        h2[q * 4 + 0] += bb.x * v; h2[q * 4 + 1] += bb.y * v;
        h2[q * 4 + 2] += bb.z * v; h2[q * 4 + 3] += bb.w * v;
      }
    }
    unsigned int ou[16];
#pragma unroll
    for (int o = 0; o < 32; o += 2) {
      float g0 = h2[o]     / (1.f + __expf(-h1[o]));
      float g1 = h2[o + 1] / (1.f + __expf(-h1[o + 1]));
      ou[o >> 1] = (unsigned int)f2bf(g0) | ((unsigned int)f2bf(g1) << 16);
    }
    uint4* dst = (uint4*)(xp + ob);
#pragma unroll
    for (int q = 0; q < 4; q++) dst[q] = ((uint4*)ou)[q];
  }
}

// K6: kv partials. grid (12 j-tiles, 4 n-splits, 16 b); block 256.
// Block tile: [128 m x 64 j] over 1024 n. Partials -> ws (no atomics).
__global__ __launch_bounds__(256) void k_kv(const unsigned short* __restrict__ xst,
    const float* __restrict__ v2p, float* __restrict__ kvpart) {
  int jt = blockIdx.x, ns = blockIdx.y, b = blockIdx.z;
  int j0 = jt * 64;
  __shared__ float sv2[32 * MM];   // 16KB
  __shared__ float sx[32 * 64];    // 8KB
  int tid = threadIdx.x;
  int mb = (tid & 15) * 8;
  int jb = (tid >> 4) * 4;
  float acc[32];
#pragma unroll
  for (int i = 0; i < 32; i++) acc[i] = 0.f;
  for (int ch = 0; ch < 32; ch++) {
    int n0 = ns * 1024 + ch * 32;
    // stage v2p rows (contiguous copy, 4096 floats)
    {
      const float4* src = (const float4*)(v2p + (size_t)n0 * MM);
      float4* dst = (float4*)sv2;
#pragma unroll
      for (int k = 0; k < 4; k++) dst[tid + k * 256] = src[tid + k * 256];
    }
    // stage x tile (32 n x 64 j, bf16 -> f32)
    {
      int nr = tid >> 3, jj8 = (tid & 7) * 8;
      uint4 xv4 = *(const uint4*)(xst + ((size_t)(b * NN) + n0 + nr) * TC + j0 + jj8);
      float* sxp = sx + nr * 64 + jj8;
      unsigned int vals[4] = {xv4.x, xv4.y, xv4.z, xv4.w};
#pragma unroll
      for (int k = 0; k < 4; k++) {
        sxp[k * 2]     = __uint_as_float((vals[k] & 0xFFFFu) << 16);
        sxp[k * 2 + 1] = __uint_as_float(vals[k] & 0xFFFF0000u);
      }
    }
    __syncthreads();
    for (int n = 0; n < 32; n++) {
      float4 xv = *(const float4*)(sx + n * 64 + jb);
      float4 a0 = *(const float4*)(sv2 + n * MM + mb);
      float4 a1 = *(const float4*)(sv2 + n * MM + mb + 4);
      float av[8] = {a0.x, a0.y, a0.z, a0.w, a1.x, a1.y, a1.z, a1.w};
      float xx[4] = {xv.x, xv.y, xv.z, xv.w};
#pragma unroll
      for (int mi = 0; mi < 8; mi++)
#pragma unroll
        for (int ji = 0; ji < 4; ji++)
          acc[mi * 4 + ji] += av[mi] * xx[ji];
    }
    __syncthreads();
  }
  float* dst = kvpart + (size_t)(ns * BB + b) * KVELEM;
#pragma unroll
  for (int mi = 0; mi < 8; mi++) {
    float4 v = make_float4(acc[mi * 4], acc[mi * 4 + 1], acc[mi * 4 + 2], acc[mi * 4 + 3]);
    *(float4*)(dst + (size_t)(mb + mi) * TC + j0 + jb) = v;
  }
}

// K6b: reduce the 4 n-split partials
__global__ __launch_bounds__(256) void k_kvred(const float4* __restrict__ part,
                                               float4* __restrict__ kv) {
  int i = blockIdx.x * 256 + threadIdx.x;  // 393216 float4s
  const int S = BB * KVELEM / 4;           // 393216
  float4 a = part[i], b = part[i + S], c = part[i + 2 * S], d = part[i + 3 * S];
  kv[i] = make_float4(a.x + b.x + c.x + d.x, a.y + b.y + c.y + d.y,
                      a.z + b.z + c.z + d.z, a.w + b.w + c.w + d.w);
}

// K7: num = v1p . kv, scale by inv_den, write transposed [B,H,N,T].
// grid (64 n-tiles, 4 c-tiles, 16 b); block 256; tile [64 n x (12 t x 16 c)].
__global__ __launch_bounds__(256) void k_num(const float* __restrict__ v1p,
    const float* __restrict__ kv, const float* __restrict__ invden,
    float* __restrict__ out) {
  int nt = blockIdx.x, ct = blockIdx.y, b = blockIdx.z;
  int n0 = nt * 64, c0 = ct * 16;
  __shared__ float sv1[64][33];    // [n][mm], padded
  __shared__ float skv[32][192];   // [mm][cc*12+t]
  int tid = threadIdx.x;
  int nb = (tid & 15) * 4;
  int cc = tid >> 4;               // 0..15
  float acc[4][12];
#pragma unroll
  for (int i = 0; i < 4; i++)
#pragma unroll
    for (int q = 0; q < 12; q++) acc[i][q] = 0.f;
  for (int m0 = 0; m0 < MM; m0 += 32) {
    {
      int n = tid >> 2, mq = (tid & 3) * 8;
      const float* src = v1p + (size_t)(n0 + n) * MM + m0 + mq;
#pragma unroll
      for (int k = 0; k < 8; k++) sv1[n][mq + k] = src[k];
    }
    {
      int mm = tid >> 3, part = tid & 7;
      const float* src = kv + (size_t)b * KVELEM + (size_t)(m0 + mm) * TC;
#pragma unroll
      for (int q = 0; q < 24; q++) {
        int jj = part * 24 + q;
        int ccq = jj / 12, t = jj - ccq * 12;
        skv[mm][jj] = src[t * HH + c0 + ccq];
      }
    }
    __syncthreads();
    for (int mm = 0; mm < 32; mm++) {
      const float* kr = &skv[mm][cc * 12];
      float4 k0 = *(const float4*)kr;
      float4 k1 = *(const float4*)(kr + 4);
      float4 k2 = *(const float4*)(kr + 8);
      float kvv[12] = {k0.x, k0.y, k0.z, k0.w, k1.x, k1.y, k1.z, k1.w,
                       k2.x, k2.y, k2.z, k2.w};
#pragma unroll
      for (int ni = 0; ni < 4; ni++) {
        float a = sv1[nb + ni][mm];
#pragma unroll
        for (int q = 0; q < 12; q++) acc[ni][q] += a * kvv[q];
      }
    }
    __syncthreads();
  }
  int c = c0 + cc;
  float* dst = out + ((size_t)(b * HH + c) * NN + n0 + nb) * TT;
#pragma unroll
  for (int ni = 0; ni < 4; ni++) {
    float idn = invden[n0 + nb + ni];
    float4 o0 = make_float4(acc[ni][0] * idn, acc[ni][1] * idn, acc[ni][2] * idn, acc[ni][3] * idn);
    float4 o1 = make_float4(acc[ni][4] * idn, acc[ni][5] * idn, acc[ni][6] * idn, acc[ni][7] * idn);
    float4 o2 = make_float4(acc[ni][8] * idn, acc[ni][9] * idn, acc[ni][10] * idn, acc[ni][11] * idn);
    float4* dp = (float4*)(dst + ni * TT);
    dp[0] = o0; dp[1] = o1; dp[2] = o2;
  }
}

extern "C" void kernel_launch(void* const* d_in, const int* in_sizes, int n_in,
                              void* d_out, int out_size, void* d_ws, size_t ws_size,
                              hipStream_t stream) {
  const float* input = (const float*)d_in[0];
  const float* nv1   = (const float*)d_in[1];
  const float* nv2   = (const float*)d_in[2];
  const float* Wi    = (const float*)d_in[3];
  const float* bi    = (const float*)d_in[4];
  const float* Wo    = (const float*)d_in[5];
  const float* bo    = (const float*)d_in[6];
  const float* proj  = (const float*)d_in[7];
  float* out = (float*)d_out;
  float* v1p = out + V1OFF;
  float* v2p = out + V2OFF;                 // holds t2 until K3 finishes it
  unsigned short* xst = (unsigned short*)d_out;  // bf16 x stash, overwritten by K7

  float* ws      = (float*)d_ws;
  float* kvpart  = ws;                       // 4*16*98304 = 6291456 floats
  float* kvbuf   = ws + 6291456;             // 1572864 floats
  float* colsum  = ws + 7864320;             // 128
  float* rowmax2 = ws + 7864448;             // 4096
  float* stab2   = ws + 7868544;             // 1
  float* invden  = ws + 7868548;             // 4096  (total ~30 MB)

  hipMemsetAsync(colsum, 0, MM * sizeof(float), stream);
  k_feat<<<NN, 128, 0, stream>>>(nv1, nv2, proj, v1p, v2p, rowmax2);
  k_stab<<<1, 256, 0, stream>>>(rowmax2, stab2);
  k_v2p<<<64, 128, 0, stream>>>(v2p, stab2, colsum);
  k_den<<<16, 256, 0, stream>>>(v1p, colsum, invden);
  k_point<<<dim3(NN / 32, BB), 384, 0, stream>>>(input, Wi, bi, Wo, bo, xst);
  k_kv<<<dim3(12, 4, BB), 256, 0, stream>>>(xst, v2p, kvpart);
  k_kvred<<<BB * KVELEM / 4 / 256, 256, 0, stream>>>((const float4*)kvpart, (float4*)kvbuf);
  k_num<<<dim3(64, 4, BB), 256, 0, stream>>>(v1p, kvbuf, invden, out);
}

// Round 2
// 777.303 us; speedup vs baseline: 1.2021x; 1.2021x over previous
//
#include <hip/hip_runtime.h>

#define BB 16
#define CIN 32
#define NN 4096
#define TT 12
#define HH 64
#define MM 128
#define DD 64
#define TC (TT*HH)            // 768
#define V1OFF 50331648        // B*H*N*T floats
#define V2OFF 50855936
#define KVELEM (MM*TC)        // 98304 per batch
#define NORMR 0.35355339059327373f   // 64^-0.25
#define RATIO 0.08838834764831845f   // 128^-0.5
#define FEPS 1e-4f

typedef __attribute__((ext_vector_type(8))) short bf16x8;
typedef __attribute__((ext_vector_type(4))) float f32x4;

union BF8 { unsigned short s[8]; bf16x8 v; };

__device__ inline float wave_max(float v) {
#pragma unroll
  for (int off = 32; off > 0; off >>= 1) v = fmaxf(v, __shfl_xor(v, off));
  return v;
}

__device__ inline unsigned short f2bf(float f) {
  unsigned int u = __float_as_uint(f);
  unsigned int r = (u + 0x7FFFu + ((u >> 16) & 1u)) >> 16;
  return (unsigned short)r;
}

// split float into hi/lo bf16 (hi + lo reconstructs to ~2^-17 rel)
__device__ inline void hilo(float v, unsigned short& h, unsigned short& l) {
  h = f2bf(v);
  float fh = __uint_as_float((unsigned int)h << 16);
  l = f2bf(v - fh);
}

// ---- tiny setup kernels -------------------------------------------------

// stack [Wi;Wo] into 128x32 and split hi/lo
__global__ __launch_bounds__(256) void k_wsplit(const float* __restrict__ Wi,
    const float* __restrict__ Wo, unsigned short* __restrict__ whi,
    unsigned short* __restrict__ wlo) {
  int idx = blockIdx.x * 256 + threadIdx.x;   // 4096
  int o = idx >> 5, c = idx & 31;
  float w = (o < 64) ? Wi[o * 32 + c] : Wo[(o - 64) * 32 + c];
  unsigned short h, l; hilo(w, h, l);
  whi[idx] = h; wlo[idx] = l;
}

// K1: per-row features. v1p final (+hi/lo planes); t2 = dash2-diag2 into v2p slot.
__global__ __launch_bounds__(128) void k_feat(const float* __restrict__ nv1,
    const float* __restrict__ nv2, const float* __restrict__ proj,
    float* __restrict__ v1p, float* __restrict__ t2, float* __restrict__ rowmax2,
    unsigned short* __restrict__ v1phi, unsigned short* __restrict__ v1plo) {
  int n = blockIdx.x, m = threadIdx.x;
  __shared__ float a1[DD], a2[DD], r1[2], r2[2];
  if (m < DD) a1[m] = nv1[n * DD + m];
  else        a2[m - DD] = nv2[n * DD + (m - DD)];
  __syncthreads();
  float s1 = 0.f, s2 = 0.f, d1 = 0.f, d2 = 0.f;
  const float* pr = proj + m * DD;
#pragma unroll 8
  for (int d = 0; d < DD; d++) {
    float x1 = a1[d], x2 = a2[d], p = pr[d];
    s1 += x1 * x1; s2 += x2 * x2;
    d1 += x1 * p;  d2 += x2 * p;
  }
  d1 *= NORMR; d2 *= NORMR;
  float diag1 = 0.0625f * s1, diag2 = 0.0625f * s2;
  float mx1 = wave_max(d1), mx2 = wave_max(d2);
  int wv = m >> 6;
  if ((m & 63) == 0) { r1[wv] = mx1; r2[wv] = mx2; }
  __syncthreads();
  mx1 = fmaxf(r1[0], r1[1]); mx2 = fmaxf(r2[0], r2[1]);
  float val = RATIO * (__expf(d1 - diag1 - mx1) + FEPS);
  v1p[n * MM + m] = val;
  unsigned short h, l; hilo(val, h, l);
  v1phi[n * MM + m] = h;
  v1plo[n * MM + m] = l;
  t2[n * MM + m] = d2 - diag2;
  if (m == 0) rowmax2[n] = mx2;
}

// K2: global max of dash2
__global__ __launch_bounds__(256) void k_stab(const float* __restrict__ rowmax2,
                                              float* __restrict__ stab2) {
  int tid = threadIdx.x;
  float mx = -3.4e38f;
  for (int i = tid; i < NN; i += 256) mx = fmaxf(mx, rowmax2[i]);
  mx = wave_max(mx);
  __shared__ float r[4];
  if ((tid & 63) == 0) r[tid >> 6] = mx;
  __syncthreads();
  if (tid == 0) stab2[0] = fmaxf(fmaxf(r[0], r[1]), fmaxf(r[2], r[3]));
}

// K3: finish v2p in place, colsum, and write transposed hi/lo planes [m][n]
__global__ __launch_bounds__(128) void k_v2p(float* __restrict__ t2v2p,
    const float* __restrict__ stab2, float* __restrict__ colsum,
    unsigned short* __restrict__ v2phiT, unsigned short* __restrict__ v2ploT) {
  int m = threadIdx.x;
  float stab = stab2[0];
  float cs = 0.f;
  int n0 = blockIdx.x * 64;   // contiguous chunk for write-combining
  for (int i = 0; i < 64; i++) {
    int n = n0 + i;
    float v = RATIO * (__expf(t2v2p[n * MM + m] - stab) + FEPS);
    t2v2p[n * MM + m] = v;
    cs += v;
    unsigned short h, l; hilo(v, h, l);
    v2phiT[(size_t)m * NN + n] = h;
    v2ploT[(size_t)m * NN + n] = l;
  }
  atomicAdd(&colsum[m], cs);
}

// K4: inv_den[n] = 1 / (v1p[n,:] . colsum)
__global__ __launch_bounds__(256) void k_den(const float* __restrict__ v1p,
    const float* __restrict__ colsum, float* __restrict__ invden) {
  __shared__ float cs[MM];
  int tid = threadIdx.x;
  if (tid < MM) cs[tid] = colsum[tid];
  __syncthreads();
  int n = blockIdx.x * 256 + tid;
  const float* vp = v1p + (size_t)n * MM;
  float s = 0.f;
#pragma unroll 8
  for (int m = 0; m < MM; m++) s += vp[m] * cs[m];
  invden[n] = 1.0f / s;
}

// ---- K5: conv+gate via MFMA. A = stacked W[128x32] hi/lo (regs), B = input.
// x stored hi/lo bf16 planes, layout [b][n/8][j=t*64+h][n%8].
__global__ __launch_bounds__(256) void k_point(const float* __restrict__ inp,
    const unsigned short* __restrict__ whi, const unsigned short* __restrict__ wlo,
    const float* __restrict__ bi, const float* __restrict__ bo,
    unsigned short* __restrict__ xhi, unsigned short* __restrict__ xlo) {
  int tid = threadIdx.x;
  int wv = tid >> 6, lane = tid & 63;
  int quad = lane >> 4, l16 = lane & 15;
  int b = blockIdx.y;
  int n = blockIdx.x * 64 + wv * 16 + l16;

  bf16x8 wh[8], wl[8];
#pragma unroll
  for (int tile = 0; tile < 8; tile++) {
    int m = tile * 16 + l16;
    wh[tile] = *(const bf16x8*)(whi + m * 32 + quad * 8);
    wl[tile] = *(const bf16x8*)(wlo + m * 32 + quad * 8);
  }
  f32x4 binit[8];
#pragma unroll
  for (int tile = 0; tile < 8; tile++) {
    const float* bp = (tile < 4) ? bi : bo;
#pragma unroll
    for (int r = 0; r < 4; r++)
      binit[tile][r] = bp[(tile & 3) * 16 + quad * 4 + r];
  }
  const float* ipb = inp + ((size_t)b * CIN + quad * 8) * (NN * TT) + (size_t)n * TT;
  for (int t = 0; t < TT; t++) {
    float xv[8];
#pragma unroll
    for (int j = 0; j < 8; j++) xv[j] = ipb[(size_t)j * (NN * TT) + t];
    BF8 xh, xl;
#pragma unroll
    for (int j = 0; j < 8; j++) {
      unsigned short h, l; hilo(xv[j], h, l);
      xh.s[j] = h; xl.s[j] = l;
    }
    f32x4 acc[8];
#pragma unroll
    for (int tile = 0; tile < 8; tile++) acc[tile] = binit[tile];
#pragma unroll
    for (int tile = 0; tile < 8; tile++) {
      acc[tile] = __builtin_amdgcn_mfma_f32_16x16x32_bf16(wh[tile], xh.v, acc[tile], 0, 0, 0);
      acc[tile] = __builtin_amdgcn_mfma_f32_16x16x32_bf16(wh[tile], xl.v, acc[tile], 0, 0, 0);
      acc[tile] = __builtin_amdgcn_mfma_f32_16x16x32_bf16(wl[tile], xh.v, acc[tile], 0, 0, 0);
    }
    size_t xbase = ((size_t)(b * (NN / 8) + (n >> 3)) * TC) * 8 + (n & 7);
#pragma unroll
    for (int i = 0; i < 4; i++) {
#pragma unroll
      for (int r = 0; r < 4; r++) {
        float h1 = acc[i][r], h2 = acc[i + 4][r];
        float g = h2 / (1.f + __expf(-h1));
        unsigned short gh, gl; hilo(g, gh, gl);
        int j = t * 64 + i * 16 + quad * 4 + r;
        xhi[xbase + (size_t)j * 8] = gh;
        xlo[xbase + (size_t)j * 8] = gl;
      }
    }
  }
}

// ---- K6: kv partials via MFMA. A = v2pT hi/lo, B = x hi/lo.
// grid (6 jt, NS, 16 b); wave handles all 8 m-tiles x 32 j.
__global__ __launch_bounds__(256) void k_kv(const unsigned short* __restrict__ xhi,
    const unsigned short* __restrict__ xlo,
    const unsigned short* __restrict__ v2phiT, const unsigned short* __restrict__ v2ploT,
    float* __restrict__ kvpart) {
  int tid = threadIdx.x, wv = tid >> 6, lane = tid & 63;
  int quad = lane >> 4, l16 = lane & 15;
  int jt = blockIdx.x, nsI = blockIdx.y, b = blockIdx.z;
  int NS = gridDim.y, kPer = NN / NS;
  int j0 = jt * 128 + wv * 32;
  f32x4 zz = {0.f, 0.f, 0.f, 0.f};
  f32x4 acc[8][2];
#pragma unroll
  for (int t = 0; t < 8; t++) { acc[t][0] = zz; acc[t][1] = zz; }
  int kend = nsI * kPer + kPer;
  for (int k0 = nsI * kPer; k0 < kend; k0 += 32) {
    bf16x8 ah[8], al[8];
#pragma unroll
    for (int tile = 0; tile < 8; tile++) {
      size_t off = (size_t)(tile * 16 + l16) * NN + k0 + quad * 8;
      ah[tile] = *(const bf16x8*)(v2phiT + off);
      al[tile] = *(const bf16x8*)(v2ploT + off);
    }
    bf16x8 bh[2], bl[2];
#pragma unroll
    for (int jf = 0; jf < 2; jf++) {
      size_t off = ((size_t)(b * (NN / 8) + (k0 >> 3) + quad) * TC + j0 + jf * 16 + l16) * 8;
      bh[jf] = *(const bf16x8*)(xhi + off);
      bl[jf] = *(const bf16x8*)(xlo + off);
    }
#pragma unroll
    for (int tile = 0; tile < 8; tile++) {
#pragma unroll
      for (int jf = 0; jf < 2; jf++) {
        acc[tile][jf] = __builtin_amdgcn_mfma_f32_16x16x32_bf16(ah[tile], bh[jf], acc[tile][jf], 0, 0, 0);
        acc[tile][jf] = __builtin_amdgcn_mfma_f32_16x16x32_bf16(ah[tile], bl[jf], acc[tile][jf], 0, 0, 0);
        acc[tile][jf] = __builtin_amdgcn_mfma_f32_16x16x32_bf16(al[tile], bh[jf], acc[tile][jf], 0, 0, 0);
      }
    }
  }
  float* dst = kvpart + (size_t)(nsI * BB + b) * KVELEM;
#pragma unroll
  for (int tile = 0; tile < 8; tile++)
#pragma unroll
    for (int jf = 0; jf < 2; jf++)
#pragma unroll
      for (int r = 0; r < 4; r++)
        dst[(size_t)(tile * 16 + quad * 4 + r) * TC + j0 + jf * 16 + l16] = acc[tile][jf][r];
}

// K6b: reduce NS partials, emit kvB hi/lo planes [b][m/8][j][m%8]
__global__ __launch_bounds__(256) void k_kvred(const float* __restrict__ kvpart,
    unsigned short* __restrict__ kvBhi, unsigned short* __restrict__ kvBlo, int NS) {
  int gid = blockIdx.x * 256 + threadIdx.x;   // 196608
  int j = gid % TC; int rest = gid / TC; int mgrp = rest & 15; int b = rest >> 4;
  float s[8];
#pragma unroll
  for (int mi = 0; mi < 8; mi++) s[mi] = 0.f;
  for (int ns = 0; ns < NS; ns++) {
    const float* p = kvpart + ((size_t)(ns * BB + b) * MM + mgrp * 8) * TC + j;
#pragma unroll
    for (int mi = 0; mi < 8; mi++) s[mi] += p[(size_t)mi * TC];
  }
  unsigned short hs[8] __attribute__((aligned(16)));
  unsigned short ls[8] __attribute__((aligned(16)));
#pragma unroll
  for (int mi = 0; mi < 8; mi++) hilo(s[mi], hs[mi], ls[mi]);
  size_t off = ((size_t)(b * 16 + mgrp) * TC + j) * 8;
  *(uint4*)(kvBhi + off) = *(const uint4*)hs;
  *(uint4*)(kvBlo + off) = *(const uint4*)ls;
}

// ---- K7: num = v1p . kv via MFMA, scale by invden, write [B,H,N,T].
// grid (128 nt, 16 b); wave: 32 n x 16 h x all 12 t.
__global__ __launch_bounds__(256) void k_num(const unsigned short* __restrict__ v1phi,
    const unsigned short* __restrict__ v1plo, const unsigned short* __restrict__ kvBhi,
    const unsigned short* __restrict__ kvBlo, const float* __restrict__ invden,
    float* __restrict__ out) {
  int tid = threadIdx.x, wv = tid >> 6, lane = tid & 63;
  int quad = lane >> 4, l16 = lane & 15;
  int nt = blockIdx.x, b = blockIdx.y;
  int n0 = nt * 32;
  int h0 = wv * 16;
  f32x4 zz = {0.f, 0.f, 0.f, 0.f};
  f32x4 acc[2][12];
#pragma unroll
  for (int t = 0; t < 12; t++) { acc[0][t] = zz; acc[1][t] = zz; }
#pragma unroll
  for (int ks = 0; ks < 4; ks++) {
    size_t aoff0 = (size_t)(n0 + l16) * MM + ks * 32 + quad * 8;
    bf16x8 a0h = *(const bf16x8*)(v1phi + aoff0);
    bf16x8 a0l = *(const bf16x8*)(v1plo + aoff0);
    bf16x8 a1h = *(const bf16x8*)(v1phi + aoff0 + 16 * MM);
    bf16x8 a1l = *(const bf16x8*)(v1plo + aoff0 + 16 * MM);
#pragma unroll
    for (int t = 0; t < 12; t++) {
      int j = t * 64 + h0 + l16;
      size_t boff = ((size_t)(b * 16 + ks * 4 + quad) * TC + j) * 8;
      bf16x8 bhv = *(const bf16x8*)(kvBhi + boff);
      bf16x8 blv = *(const bf16x8*)(kvBlo + boff);
      acc[0][t] = __builtin_amdgcn_mfma_f32_16x16x32_bf16(a0h, bhv, acc[0][t], 0, 0, 0);
      acc[0][t] = __builtin_amdgcn_mfma_f32_16x16x32_bf16(a0h, blv, acc[0][t], 0, 0, 0);
      acc[0][t] = __builtin_amdgcn_mfma_f32_16x16x32_bf16(a0l, bhv, acc[0][t], 0, 0, 0);
      acc[1][t] = __builtin_amdgcn_mfma_f32_16x16x32_bf16(a1h, bhv, acc[1][t], 0, 0, 0);
      acc[1][t] = __builtin_amdgcn_mfma_f32_16x16x32_bf16(a1h, blv, acc[1][t], 0, 0, 0);
      acc[1][t] = __builtin_amdgcn_mfma_f32_16x16x32_bf16(a1l, bhv, acc[1][t], 0, 0, 0);
    }
  }
  int h = h0 + l16;
#pragma unroll
  for (int s = 0; s < 2; s++) {
#pragma unroll
    for (int r = 0; r < 4; r++) {
      int n = n0 + s * 16 + quad * 4 + r;
      float idn = invden[n];
      float o[12];
#pragma unroll
      for (int t = 0; t < 12; t++) o[t] = acc[s][t][r] * idn;
      float* dst = out + ((size_t)(b * HH + h) * NN + n) * TT;
      *(float4*)(dst) = make_float4(o[0], o[1], o[2], o[3]);
      *(float4*)(dst + 4) = make_float4(o[4], o[5], o[6], o[7]);
      *(float4*)(dst + 8) = make_float4(o[8], o[9], o[10], o[11]);
    }
  }
}

extern "C" void kernel_launch(void* const* d_in, const int* in_sizes, int n_in,
                              void* d_out, int out_size, void* d_ws, size_t ws_size,
                              hipStream_t stream) {
  const float* input = (const float*)d_in[0];
  const float* nv1   = (const float*)d_in[1];
  const float* nv2   = (const float*)d_in[2];
  const float* Wi    = (const float*)d_in[3];
  const float* bi    = (const float*)d_in[4];
  const float* Wo    = (const float*)d_in[5];
  const float* bo    = (const float*)d_in[6];
  const float* proj  = (const float*)d_in[7];
  float* out = (float*)d_out;
  float* v1p = out + V1OFF;
  float* v2p = out + V2OFF;
  // x hi/lo planes alias the out0 region exactly (50331648 shorts each)
  unsigned short* xhi = (unsigned short*)d_out;
  unsigned short* xlo = xhi + 50331648;

  char* wsb = (char*)d_ws;
  const size_t MB = 1 << 20;
  unsigned short* v2phiT = (unsigned short*)(wsb + 0 * MB);
  unsigned short* v2ploT = (unsigned short*)(wsb + 1 * MB);
  unsigned short* v1phi  = (unsigned short*)(wsb + 2 * MB);
  unsigned short* v1plo  = (unsigned short*)(wsb + 3 * MB);
  unsigned short* whi    = (unsigned short*)(wsb + 4 * MB);
  unsigned short* wlo    = (unsigned short*)(wsb + 4 * MB + 8192);
  float* colsum  = (float*)(wsb + 4 * MB + 16384);
  float* rowmax2 = (float*)(wsb + 4 * MB + 16384 + 512);
  float* stab2   = (float*)(wsb + 4 * MB + 16384 + 512 + 16384);
  float* invden  = (float*)(wsb + 5 * MB);
  unsigned short* kvBhi = (unsigned short*)(wsb + 6 * MB);
  unsigned short* kvBlo = (unsigned short*)(wsb + 10 * MB);
  float* kvpart = (float*)(wsb + 14 * MB);

  // adaptive n-split for kv partials based on available ws
  size_t partBytes = (size_t)BB * KVELEM * 4;
  size_t avail = (ws_size > 14 * MB) ? ws_size - 14 * MB : 0;
  int NS = (avail >= 8 * partBytes) ? 8 : (avail >= 4 * partBytes ? 4 : 2);

  hipMemsetAsync(colsum, 0, MM * sizeof(float), stream);
  k_wsplit<<<16, 256, 0, stream>>>(Wi, Wo, whi, wlo);
  k_feat<<<NN, 128, 0, stream>>>(nv1, nv2, proj, v1p, v2p, rowmax2, v1phi, v1plo);
  k_stab<<<1, 256, 0, stream>>>(rowmax2, stab2);
  k_v2p<<<64, 128, 0, stream>>>(v2p, stab2, colsum, v2phiT, v2ploT);
  k_den<<<16, 256, 0, stream>>>(v1p, colsum, invden);
  k_point<<<dim3(64, 16), 256, 0, stream>>>(input, whi, wlo, bi, bo, xhi, xlo);
  k_kv<<<dim3(6, NS, 16), 256, 0, stream>>>(xhi, xlo, v2phiT, v2ploT, kvpart);
  k_kvred<<<768, 256, 0, stream>>>(kvpart, kvBhi, kvBlo, NS);
  k_num<<<dim3(128, 16), 256, 0, stream>>>(v1phi, v1plo, kvBhi, kvBlo, invden, out);
}